// Round 11
// baseline (997.451 us; speedup 1.0000x reference)
//
#include <hip/hip_runtime.h>
#include <hip/hip_cooperative_groups.h>

namespace cg = cooperative_groups;

#define NN 256
#define MM 65536
#define TBL 131072
#define TBL_MASK (TBL - 1)
#define NTHREADS 131072u
#define NBLOCKS 512

// ---------------- workspace byte offsets (mega path) ----------------
#define OFF_TK0 ((size_t)0)
#define OFF_TK1 (OFF_TK0 + (size_t)TBL * 8)
#define OFF_MPA (OFF_TK1 + (size_t)TBL * 8)
#define OFF_MPB (OFF_MPA + (size_t)TBL * 4)
#define OFF_CNA (OFF_MPB + (size_t)TBL * 4)
#define OFF_CNB (OFF_CNA + (size_t)TBL * 4)
#define OFF_FLA (OFF_CNB + (size_t)TBL * 4)
#define OFF_FLB (OFF_FLA + (size_t)MM * 4)
#define OFF_A (OFF_FLB + (size_t)MM * 4)
#define OFF_MP0 (OFF_A + (size_t)MM * 4)
#define OFF_C0 (OFF_MP0 + 2048)
#define ZERO_END (OFF_C0 + 2048)
#define OFF_SLOT (ZERO_END)
#define OFF_LSC (OFF_SLOT + (size_t)MM * 4)
#define OFF_LAB (OFF_LSC + (size_t)MM * 4)
#define OFF_RS (OFF_LAB + (size_t)MM * 4)
#define OFF_CS (OFF_RS + (size_t)MM * 4)
#define OFF_RV (OFF_CS + (size_t)MM * 4)
#define OFF_CV (OFF_RV + 1024)

__device__ __forceinline__ unsigned key0m(const int* x, const int* A, int i, int j, int m) {
    return ((unsigned)x[i] << 5) | ((unsigned)x[j] << 1) | (unsigned)A[m];
}

__device__ __forceinline__ void bitonic256(int* s, int t) {
    for (int k = 2; k <= NN; k <<= 1) {
        for (int jj = k >> 1; jj > 0; jj >>= 1) {
            int ixj = t ^ jj;
            if (ixj > t) {
                int a = s[t], b = s[ixj];
                bool asc = ((t & k) == 0);
                if (asc ? (a > b) : (a < b)) {
                    s[t] = b;
                    s[ixj] = a;
                }
            }
            __syncthreads();
        }
    }
}

// ==================== mega cooperative kernel ====================

struct MegaP {
    const int* x;
    const int* ei;
    int E;
    int* out;
    int out_size;
    char* ws;
};

__global__ __launch_bounds__(256, 2) void mega(MegaP p) {
    cg::grid_group grid = cg::this_grid();
    const int t = threadIdx.x;
    const int b = blockIdx.x;
    const int tid = b * 256 + t;
    const int lane = t & 63, wid = t >> 6;

    char* ws = p.ws;
    unsigned long long* tkL[2] = {(unsigned long long*)(ws + OFF_TK0),
                                  (unsigned long long*)(ws + OFF_TK1)};
    unsigned* mpL[2] = {(unsigned*)(ws + OFF_MPA), (unsigned*)(ws + OFF_MPB)};
    unsigned* cntL[2] = {(unsigned*)(ws + OFF_CNA), (unsigned*)(ws + OFF_CNB)};
    unsigned* flagsL[2] = {(unsigned*)(ws + OFF_FLA), (unsigned*)(ws + OFF_FLB)};
    int* A = (int*)(ws + OFF_A);
    unsigned* mp0 = (unsigned*)(ws + OFF_MP0);
    unsigned* c0 = (unsigned*)(ws + OFF_C0);
    unsigned* slotidx = (unsigned*)(ws + OFF_SLOT);
    unsigned* lscan = (unsigned*)(ws + OFF_LSC);
    int* lab = (int*)(ws + OFF_LAB);
    int* rs = (int*)(ws + OFF_RS);
    int* cs = (int*)(ws + OFF_CS);
    int* rvec = (int*)(ws + OFF_RV);
    int* cvec = (int*)(ws + OFF_CV);
    unsigned* bsum = cvec ? (unsigned*)(ws + OFF_CV + 1024) : nullptr;  // 512*4 after cvec

    __shared__ unsigned smem[512];     // working buffer (sort / scans)
    __shared__ unsigned rank0_s[512];  // persistent layer-0 label table
    __shared__ unsigned bofs_s[512];   // per-block exclusive block offsets

    // ---- P0: zero workspace tables + output ----
    {
        uint4 z;
        z.x = z.y = z.z = z.w = 0u;
        uint4* zw = (uint4*)ws;
        const unsigned nzq = (unsigned)(ZERO_END / 16);
        for (unsigned q = tid; q < nzq; q += NTHREADS) zw[q] = z;
        uint4* zo = (uint4*)p.out;
        const unsigned noq = (unsigned)(p.out_size / 4);
        for (unsigned q = tid; q < noq; q += NTHREADS) zo[q] = z;
    }
    grid.sync();

    // ---- adjacency ----
    if (tid < p.E) {
        int s0 = p.ei[tid];
        int d0 = p.ei[p.E + tid];
        A[s0 * NN + d0] = 1;
    }
    grid.sync();

    // ---- initial-coloring key pass (minpos encoded as max(~pos)) ----
    if (tid < MM) {
        int i = tid >> 8, j = tid & 255;
        unsigned key = key0m(p.x, A, i, j, tid);
        unsigned pos = (i == j) ? (unsigned)(NN * (NN - 1) + i)
                                : (unsigned)(i * (NN - 1) + (j < i ? j : j - 1));
        atomicMax(&mp0[key], ~pos);
        atomicAdd(&c0[key], 1u);
    }
    grid.sync();

    // ---- rank0:每 block redundantly builds the 512-entry rank table in LDS ----
    {
        for (int k = t; k < 512; k += 256) {
            unsigned c = c0[k];
            smem[k] = c ? ~mp0[k] : 0xFFFFFFFFu;
        }
        __syncthreads();
        for (int k = t; k < 512; k += 256) {
            unsigned c = c0[k];
            unsigned rk = 0;
            if (c) {
                unsigned my = smem[k];
                for (int kk = 0; kk < 512; ++kk) rk += (smem[kk] < my) ? 1u : 0u;
                if (b == 0) p.out[rk] = (int)c;  // histogram 0
            }
            rank0_s[k] = rk;
        }
        __syncthreads();
    }

    // ---- refinement layers ----
    for (int layer = 0; layer < 2; ++layer) {
        unsigned long long* tk = tkL[layer];
        unsigned* mp = mpL[layer];
        unsigned* cnt = cntL[layer];
        unsigned* flags = flagsL[layer];
        int* hist = p.out + (size_t)(layer + 1) * MM;

        // (a) sort rows & cols: block b -> (mode = b>>8, i = b&255)
        {
            int* s32 = (int*)smem;
            int i = b & 255, mode = b >> 8;
            if (t == 0) (mode ? cvec : rvec)[i] = i;
            int m = mode ? (t * NN + i) : (i * NN + t);
            int v = (layer == 0)
                        ? (int)rank0_s[key0m(p.x, A, mode ? t : i, mode ? i : t, m)]
                        : lab[m];
            s32[t] = v;
            __syncthreads();
            bitonic256(s32, t);
            (mode ? cs : rs)[i * NN + t] = s32[t];
            __syncthreads();
        }
        grid.sync();

        // (b) representative: one wave per (rc,i,j), grid-stride over 131072 tasks
        {
            int gw = tid >> 6;
            for (unsigned task = (unsigned)gw; task < 131072u; task += 2048u) {
                unsigned rc = task >> 16;
                unsigned rem = task & 65535u;
                int i = (int)(rem >> 8), j = (int)(rem & 255u);
                if (j < i) {
                    const int* S = rc ? cs : rs;
                    const int* ri = S + i * NN;
                    const int* rj = S + j * NN;
                    bool eq = true;
#pragma unroll
                    for (int k2 = 0; k2 < NN; k2 += 64)
                        eq = eq && (ri[lane + k2] == rj[lane + k2]);
                    if (__all(eq)) {
                        if (lane == 0) atomicMin((rc ? cvec : rvec) + i, j);
                    }
                }
            }
        }
        grid.sync();

        // (c) exact relabel via hash insert
        if (tid < MM) {
            int i = tid >> 8, j = tid & 255;
            unsigned l = (layer == 0) ? rank0_s[key0m(p.x, A, i, j, tid)] : (unsigned)lab[tid];
            unsigned key = l | ((unsigned)rvec[i] << 16) | ((unsigned)cvec[j] << 24);
            unsigned long long kk = (unsigned long long)key + 1ull;
            unsigned h = ((key * 2654435761u) >> 15) & TBL_MASK;
            for (;;) {
                unsigned long long prev = atomicCAS(&tk[h], 0ull, kk);
                if (prev == 0ull || prev == kk) break;
                h = (h + 1) & TBL_MASK;
            }
            slotidx[tid] = h;
            atomicMax(&mp[h], ~(unsigned)tid);
            atomicAdd(&cnt[h], 1u);
        }
        grid.sync();

        // (d) mark first-occurrence positions
        if (tk[tid]) flags[~mp[tid]] = 1u;  // tid spans exactly TBL
        grid.sync();

        // (e1) block-local exclusive scan of this block's 128-flag chunk
        {
            unsigned v = (t < 128) ? flags[b * 128 + t] : 0u;
            unsigned inc = v;
#pragma unroll
            for (int off = 1; off < 64; off <<= 1) {
                unsigned n = __shfl_up(inc, off, 64);
                if (lane >= off) inc += n;
            }
            if (lane == 63) smem[wid] = inc;
            __syncthreads();
            if (t < 128) lscan[b * 128 + t] = (inc - v) + (wid == 1 ? smem[0] : 0u);
            if (t == 0) bsum[b] = smem[0] + smem[1];
            __syncthreads();
        }
        grid.sync();

        // (f) finish: per-block redundant scan of bsum -> bofs_s, then writes
        {
            smem[t] = bsum[t];
            smem[t + 256] = bsum[t + 256];
            __syncthreads();
            for (int off = 1; off < 512; off <<= 1) {
                unsigned a0 = (t >= off) ? smem[t - off] : 0u;
                unsigned a1 = ((t + 256) >= off) ? smem[t + 256 - off] : 0u;
                __syncthreads();
                smem[t] += a0;
                smem[t + 256] += a1;
                __syncthreads();
            }
            bofs_s[t] = smem[t] - bsum[t];  // exclusive block offsets
            bofs_s[t + 256] = smem[t + 256] - bsum[t + 256];
            __syncthreads();

            if (tid < MM) {
                unsigned q = ~mp[slotidx[tid]];
                lab[tid] = (int)(lscan[q] + bofs_s[q >> 7]);
            }
            if (tk[tid]) {
                unsigned q = ~mp[tid];
                hist[lscan[q] + bofs_s[q >> 7]] = (int)cnt[tid];
            }
        }
        grid.sync();
    }
}

// ==================== legacy multi-kernel fallback (round-6, proven) ====================

__global__ void build_adj(const int* __restrict__ ei, int* __restrict__ A, int E) {
    int e = blockIdx.x * blockDim.x + threadIdx.x;
    if (e < E) {
        int s = ei[e];
        int d = ei[E + e];
        A[s * NN + d] = 1;
    }
}

__global__ void init_key_pass(const int* __restrict__ x, const int* __restrict__ A,
                              unsigned* __restrict__ mp0, unsigned* __restrict__ c0) {
    int m = blockIdx.x * blockDim.x + threadIdx.x;
    int i = m >> 8, j = m & 255;
    unsigned key = key0m(x, A, i, j, m);
    unsigned pos = (i == j) ? (unsigned)(NN * (NN - 1) + i)
                            : (unsigned)(i * (NN - 1) + (j < i ? j : j - 1));
    atomicMax(&mp0[key], ~pos);
    atomicAdd(&c0[key], 1u);
}

__global__ void rank0_fused(const unsigned* __restrict__ mp0, const unsigned* __restrict__ c0,
                            unsigned* __restrict__ rank0, int* __restrict__ hist) {
    __shared__ unsigned pos_s[512];
    int k = threadIdx.x;
    unsigned c = c0[k];
    pos_s[k] = c ? ~mp0[k] : 0xFFFFFFFFu;
    __syncthreads();
    if (c) {
        unsigned my = pos_s[k];
        int rk = 0;
        for (int kk = 0; kk < 512; ++kk) rk += (pos_s[kk] < my);
        rank0[k] = (unsigned)rk;
        hist[rk] = (int)c;
    }
}

__global__ void write_labels0(const int* __restrict__ x, const int* __restrict__ A,
                              const unsigned* __restrict__ rank0, int* __restrict__ labels) {
    int m = blockIdx.x * blockDim.x + threadIdx.x;
    int i = m >> 8, j = m & 255;
    labels[m] = (int)rank0[key0m(x, A, i, j, m)];
}

__global__ void sort_both(const int* __restrict__ labels, int* __restrict__ rowsorted,
                          int* __restrict__ colsorted, int* __restrict__ rvec,
                          int* __restrict__ cvec) {
    __shared__ int s[NN];
    int bx = blockIdx.x;
    int i = bx & 255, mode = bx >> 8, t = threadIdx.x;
    int* rep = mode ? cvec : rvec;
    int* dst = mode ? colsorted : rowsorted;
    if (t == 0) rep[i] = i;
    s[t] = mode ? labels[t * NN + i] : labels[i * NN + t];
    __syncthreads();
    bitonic256(s, t);
    dst[i * NN + t] = s[t];
}

__global__ void rep_pairs_both(const int* __restrict__ rowsorted,
                               const int* __restrict__ colsorted, int* __restrict__ rvec,
                               int* __restrict__ cvec) {
    int i = blockIdx.x;
    int wid = threadIdx.x >> 6;
    int lane = threadIdx.x & 63;
    int j = (blockIdx.y << 2) + wid;
    if (j >= i) return;
    const int* sorted = blockIdx.z ? colsorted : rowsorted;
    int* rep = blockIdx.z ? cvec : rvec;
    const int* ri = sorted + i * NN;
    const int* rj = sorted + j * NN;
    bool eq = true;
#pragma unroll
    for (int k = 0; k < NN; k += 64) eq = eq && (ri[lane + k] == rj[lane + k]);
    if (__all(eq)) {
        if (lane == 0) atomicMin(&rep[i], j);
    }
}

__global__ void relabel_insert(const int* __restrict__ labels, const int* __restrict__ r,
                               const int* __restrict__ c, unsigned long long* __restrict__ tk,
                               unsigned* __restrict__ mp, unsigned* __restrict__ cnt,
                               unsigned* __restrict__ slotidx) {
    int m = blockIdx.x * blockDim.x + threadIdx.x;
    int i = m >> 8, j = m & 255;
    unsigned key = (unsigned)labels[m] | ((unsigned)r[i] << 16) | ((unsigned)c[j] << 24);
    unsigned long long kk = (unsigned long long)key + 1ull;
    unsigned h = ((key * 2654435761u) >> 15) & TBL_MASK;
    for (;;) {
        unsigned long long prev = atomicCAS(&tk[h], 0ull, kk);
        if (prev == 0ull || prev == kk) break;
        h = (h + 1) & TBL_MASK;
    }
    slotidx[m] = h;
    atomicMax(&mp[h], ~(unsigned)m);
    atomicAdd(&cnt[h], 1u);
}

__global__ void mark_slots(const unsigned long long* __restrict__ tk,
                           const unsigned* __restrict__ mp, unsigned* __restrict__ flags) {
    int s = blockIdx.x * blockDim.x + threadIdx.x;
    if (tk[s]) flags[~mp[s]] = 1u;
}

__global__ void scan64k(const unsigned* __restrict__ in, unsigned* __restrict__ out) {
    __shared__ unsigned wsums[16];
    __shared__ unsigned carry_s;
    int t = threadIdx.x;
    int lane = t & 63, wid = t >> 6;
    if (t == 0) carry_s = 0;
    __syncthreads();
    for (int tile = 0; tile < 16; ++tile) {
        uint4 v = ((const uint4*)in)[tile * 1024 + t];
        unsigned s0 = v.x, s1 = s0 + v.y, s2 = s1 + v.z, q = s2 + v.w;
        unsigned inc = q;
#pragma unroll
        for (int off = 1; off < 64; off <<= 1) {
            unsigned n = __shfl_up(inc, off, 64);
            if (lane >= off) inc += n;
        }
        if (lane == 63) wsums[wid] = inc;
        __syncthreads();
        if (t < 16) {
            unsigned w = wsums[t];
            unsigned wi = w;
#pragma unroll
            for (int off = 1; off < 16; off <<= 1) {
                unsigned n = __shfl_up(wi, off, 64);
                if (lane >= off) wi += n;
            }
            wsums[t] = wi - w;
        }
        __syncthreads();
        unsigned base = carry_s + wsums[wid] + (inc - q);
        uint4 o;
        o.x = base;
        o.y = base + s0;
        o.z = base + s1;
        o.w = base + s2;
        ((uint4*)out)[tile * 1024 + t] = o;
        __syncthreads();
        if (t == 1023) carry_s += wsums[15] + inc;
        __syncthreads();
    }
}

__global__ void finish_layer(const unsigned long long* __restrict__ tk,
                             const unsigned* __restrict__ mp, const unsigned* __restrict__ cnt,
                             const unsigned* __restrict__ rankat,
                             const unsigned* __restrict__ slotidx, int* __restrict__ hist,
                             int* __restrict__ labels2) {
    int s = blockIdx.x * blockDim.x + threadIdx.x;
    if (s < MM) labels2[s] = (int)rankat[~mp[slotidx[s]]];
    if (tk[s]) hist[rankat[~mp[s]]] = (int)cnt[s];
}

extern "C" void kernel_launch(void* const* d_in, const int* in_sizes, int n_in,
                              void* d_out, int out_size, void* d_ws, size_t ws_size,
                              hipStream_t stream) {
    const int* x = (const int*)d_in[0];
    const int* ei = (const int*)d_in[1];
    const int E = in_sizes[1] / 2;
    int* out = (int*)d_out;

    // ---- try the single cooperative mega-kernel first ----
    MegaP hp;
    hp.x = x;
    hp.ei = ei;
    hp.E = E;
    hp.out = out;
    hp.out_size = out_size;
    hp.ws = (char*)d_ws;
    void* args[] = {&hp};
    hipError_t err = hipLaunchCooperativeKernel((const void*)mega, dim3(NBLOCKS), dim3(256),
                                                args, 0, stream);
    if (err == hipSuccess) return;

    // ---- fallback: proven multi-kernel path (round-6) ----
    char* w = (char*)d_ws;
    size_t off = 0;
    auto alloc = [&](size_t bytes) -> void* {
        void* p = w + off;
        off = (off + bytes + 511) & ~(size_t)511;
        return p;
    };
    unsigned long long* tkL[2] = {(unsigned long long*)alloc(TBL * 8),
                                  (unsigned long long*)alloc(TBL * 8)};
    unsigned* mpL[2] = {(unsigned*)alloc(TBL * 4), (unsigned*)alloc(TBL * 4)};
    unsigned* cntL[2] = {(unsigned*)alloc(TBL * 4), (unsigned*)alloc(TBL * 4)};
    unsigned* flagsL[2] = {(unsigned*)alloc(MM * 4), (unsigned*)alloc(MM * 4)};
    int* A = (int*)alloc(MM * 4);
    unsigned* mp0 = (unsigned*)alloc(512 * 4);
    unsigned* c0 = (unsigned*)alloc(512 * 4);
    size_t zero_end = off;
    unsigned* slotidx = (unsigned*)alloc(MM * 4);
    unsigned* rankat = (unsigned*)alloc(MM * 4);
    int* labels = (int*)alloc(MM * 4);
    int* labels2 = (int*)alloc(MM * 4);
    int* rowsorted = (int*)alloc(MM * 4);
    int* colsorted = (int*)alloc(MM * 4);
    int* rvec = (int*)alloc(NN * 4);
    int* cvec = (int*)alloc(NN * 4);
    unsigned* rank0 = (unsigned*)alloc(512 * 4);

    (void)hipMemsetAsync(d_ws, 0, zero_end, stream);
    (void)hipMemsetAsync(d_out, 0, (size_t)out_size * sizeof(int), stream);

    build_adj<<<(E + 255) / 256, 256, 0, stream>>>(ei, A, E);
    init_key_pass<<<MM / 256, 256, 0, stream>>>(x, A, mp0, c0);
    rank0_fused<<<1, 512, 0, stream>>>(mp0, c0, rank0, out);
    write_labels0<<<MM / 256, 256, 0, stream>>>(x, A, rank0, labels);

    int* lab = labels;
    int* lab2 = labels2;
    for (int layer = 0; layer < 2; ++layer) {
        sort_both<<<2 * NN, NN, 0, stream>>>(lab, rowsorted, colsorted, rvec, cvec);
        rep_pairs_both<<<dim3(NN, NN / 4, 2), 256, 0, stream>>>(rowsorted, colsorted, rvec, cvec);
        relabel_insert<<<MM / 256, 256, 0, stream>>>(lab, rvec, cvec, tkL[layer], mpL[layer],
                                                     cntL[layer], slotidx);
        mark_slots<<<TBL / 256, 256, 0, stream>>>(tkL[layer], mpL[layer], flagsL[layer]);
        scan64k<<<1, 1024, 0, stream>>>(flagsL[layer], rankat);
        finish_layer<<<TBL / 256, 256, 0, stream>>>(tkL[layer], mpL[layer], cntL[layer], rankat,
                                                    slotidx, out + (size_t)(layer + 1) * MM, lab2);
        int* tmp = lab;
        lab = lab2;
        lab2 = tmp;
    }
}

// Round 13
// 200.530 us; speedup vs baseline: 4.9741x; 4.9741x over previous
//
#include <hip/hip_runtime.h>

#define NN 256
#define MM 65536
#define TBL 131072
#define TBL_MASK (TBL - 1)

__device__ __forceinline__ unsigned key0m(const int* x, const int* A, int i, int j, int m) {
    return ((unsigned)x[i] << 5) | ((unsigned)x[j] << 1) | (unsigned)A[m];
}

__device__ __forceinline__ unsigned long long mix64(unsigned v) {
    unsigned long long z = (unsigned long long)v + 0x9E3779B97F4A7C15ull;
    z = (z ^ (z >> 30)) * 0xBF58476D1CE4E5B9ull;
    z = (z ^ (z >> 27)) * 0x94D049BB133111EBull;
    return z ^ (z >> 31);
}

// ---------------- phase kernels ----------------

__global__ void build_adj(const int* __restrict__ ei, int* __restrict__ A, int E) {
    int e = blockIdx.x * blockDim.x + threadIdx.x;
    if (e < E) {
        int s = ei[e];
        int d = ei[E + e];
        A[s * NN + d] = 1;
    }
}

// key pass for initial coloring; also zeroes histogram 0 (minpos = max(~pos), zero-init)
__global__ void init_key_pass(const int* __restrict__ x, const int* __restrict__ A,
                              unsigned* __restrict__ mp0, unsigned* __restrict__ c0,
                              int* __restrict__ hist0) {
    int m = blockIdx.x * blockDim.x + threadIdx.x;
    hist0[m] = 0;
    int i = m >> 8, j = m & 255;
    unsigned key = key0m(x, A, i, j, m);
    // torch order: permutations (i != j) lexicographically, then the diagonal
    unsigned pos = (i == j) ? (unsigned)(NN * (NN - 1) + i)
                            : (unsigned)(i * (NN - 1) + (j < i ? j : j - 1));
    atomicMax(&mp0[key], ~pos);
    atomicAdd(&c0[key], 1u);
}

// one block, 512 threads: rank groups by first occurrence via O(512^2) counting
__global__ void rank0_fused(const unsigned* __restrict__ mp0, const unsigned* __restrict__ c0,
                            unsigned* __restrict__ rank0, int* __restrict__ hist) {
    __shared__ unsigned pos_s[512];
    int k = threadIdx.x;
    unsigned c = c0[k];
    pos_s[k] = c ? ~mp0[k] : 0xFFFFFFFFu;
    __syncthreads();
    if (c) {
        unsigned my = pos_s[k];
        int rk = 0;
        for (int kk = 0; kk < 512; ++kk) rk += (pos_s[kk] < my);
        rank0[k] = (unsigned)rk;
        hist[rk] = (int)c;
    }
}

// commutative 64-bit multiset hash of each row (blocks 0..255) and col (256..511)
__global__ void hash_both(const int* __restrict__ x, const int* __restrict__ A,
                          const unsigned* __restrict__ rank0, const int* __restrict__ lab,
                          int layer, unsigned long long* __restrict__ rowhash,
                          unsigned long long* __restrict__ colhash) {
    __shared__ unsigned long long hs[256];
    int b = blockIdx.x, t = threadIdx.x;
    int i = b & 255, mode = b >> 8;
    int m = mode ? t * NN + i : i * NN + t;
    unsigned lv = (layer == 0)
                      ? rank0[key0m(x, A, mode ? t : i, mode ? i : t, m)]
                      : (unsigned)lab[m];
    hs[t] = mix64(lv);
    __syncthreads();
    for (int off = 128; off > 0; off >>= 1) {
        if (t < off) hs[t] += hs[t + off];
        __syncthreads();
    }
    if (t == 0) (mode ? colhash : rowhash)[i] = hs[0];
}

// rep[i] = min j with equal multiset hash; 1 block, 512 threads (t>=256 -> col mode)
__global__ void rep_hash(const unsigned long long* __restrict__ rowhash,
                         const unsigned long long* __restrict__ colhash,
                         int* __restrict__ rvec, int* __restrict__ cvec) {
    __shared__ unsigned long long hh[512];
    int t = threadIdx.x;
    hh[t] = (t < 256) ? rowhash[t] : colhash[t - 256];
    __syncthreads();
    int mode = t >> 8, i = t & 255, base = mode << 8;
    unsigned long long my = hh[base + i];
    int r = i;
    for (int j = 0; j < i; ++j) {
        if (hh[base + j] == my) {
            r = j;
            break;
        }
    }
    (mode ? cvec : rvec)[i] = r;
}

// exact relabel via hash-table insert (key injective: label|rowclass|colclass)
__global__ void relabel_insert(const int* __restrict__ x, const int* __restrict__ A,
                               const unsigned* __restrict__ rank0, const int* __restrict__ lab,
                               int layer, const int* __restrict__ r, const int* __restrict__ c,
                               unsigned long long* __restrict__ tk, unsigned* __restrict__ mp,
                               unsigned* __restrict__ cnt, unsigned* __restrict__ slotidx) {
    int m = blockIdx.x * blockDim.x + threadIdx.x;
    int i = m >> 8, j = m & 255;
    unsigned l = (layer == 0) ? rank0[key0m(x, A, i, j, m)] : (unsigned)lab[m];
    unsigned key = l | ((unsigned)r[i] << 16) | ((unsigned)c[j] << 24);
    unsigned long long kk = (unsigned long long)key + 1ull;  // 0 = empty
    unsigned h = ((key * 2654435761u) >> 15) & TBL_MASK;
    for (;;) {
        unsigned long long prev = atomicCAS(&tk[h], 0ull, kk);
        if (prev == 0ull || prev == kk) break;
        h = (h + 1) & TBL_MASK;
    }
    slotidx[m] = h;
    atomicMax(&mp[h], ~(unsigned)m);  // encoded min-pos, zero-init
    atomicAdd(&cnt[h], 1u);
}

// set first-occurrence bits in a 2048-word bitmap; also zero this layer's histogram
__global__ void mark_bm(const unsigned long long* __restrict__ tk,
                        const unsigned* __restrict__ mp, unsigned* __restrict__ bm,
                        int* __restrict__ hist) {
    int s = blockIdx.x * blockDim.x + threadIdx.x;  // spans TBL
    if (s < MM) hist[s] = 0;
    if (tk[s]) {
        unsigned q = ~mp[s];
        atomicOr(&bm[q >> 5], 1u << (q & 31));
    }
}

// per-block redundant prefix-popcount of the bitmap -> rank(); write labels + histogram
__global__ void finish_bm(const unsigned long long* __restrict__ tk,
                          const unsigned* __restrict__ mp, const unsigned* __restrict__ cnt,
                          const unsigned* __restrict__ bm, const unsigned* __restrict__ slotidx,
                          int* __restrict__ hist, int* __restrict__ lab) {
    __shared__ unsigned bw[2048];  // bitmap words
    __shared__ unsigned wb[2048];  // per-word exclusive popcount base
    __shared__ unsigned ts[256];   // per-thread sums
    int t = threadIdx.x;
    for (int k = t; k < 2048; k += 256) bw[k] = bm[k];
    __syncthreads();
    unsigned pc[8], s = 0;
#pragma unroll
    for (int k = 0; k < 8; ++k) {
        pc[k] = (unsigned)__popc(bw[t * 8 + k]);
        s += pc[k];
    }
    ts[t] = s;
    __syncthreads();
    for (int off = 1; off < 256; off <<= 1) {
        unsigned v = (t >= off) ? ts[t - off] : 0u;
        __syncthreads();
        ts[t] += v;
        __syncthreads();
    }
    unsigned run = ts[t] - s;  // exclusive base for this thread's 8 words
#pragma unroll
    for (int k = 0; k < 8; ++k) {
        wb[t * 8 + k] = run;
        run += pc[k];
    }
    __syncthreads();

    int sdx = blockIdx.x * 256 + t;  // spans TBL
    if (sdx < MM) {
        unsigned q = ~mp[slotidx[sdx]];
        lab[sdx] = (int)(wb[q >> 5] + (unsigned)__popc(bw[q >> 5] & ((1u << (q & 31)) - 1u)));
    }
    if (tk[sdx]) {
        unsigned q = ~mp[sdx];
        unsigned rk = wb[q >> 5] + (unsigned)__popc(bw[q >> 5] & ((1u << (q & 31)) - 1u));
        hist[rk] = (int)cnt[sdx];
    }
}

extern "C" void kernel_launch(void* const* d_in, const int* in_sizes, int n_in,
                              void* d_out, int out_size, void* d_ws, size_t ws_size,
                              hipStream_t stream) {
    const int* x = (const int*)d_in[0];
    const int* ei = (const int*)d_in[1];
    const int E = in_sizes[1] / 2;
    int* out = (int*)d_out;  // int32 histograms

    // ---- workspace carve-up (512B aligned) ----
    char* w = (char*)d_ws;
    size_t off = 0;
    auto alloc = [&](size_t bytes) -> void* {
        void* p = w + off;
        off = (off + bytes + 511) & ~(size_t)511;
        return p;
    };
    // zero region: one memset covers [0, zero_end)
    unsigned long long* tkL[2] = {(unsigned long long*)alloc(TBL * 8),
                                  (unsigned long long*)alloc(TBL * 8)};
    unsigned* mpL[2] = {(unsigned*)alloc(TBL * 4), (unsigned*)alloc(TBL * 4)};
    unsigned* cntL[2] = {(unsigned*)alloc(TBL * 4), (unsigned*)alloc(TBL * 4)};
    unsigned* bmL[2] = {(unsigned*)alloc(2048 * 4), (unsigned*)alloc(2048 * 4)};
    int* A = (int*)alloc(MM * 4);
    unsigned* mp0 = (unsigned*)alloc(512 * 4);
    unsigned* c0 = (unsigned*)alloc(512 * 4);
    size_t zero_end = off;
    // non-zeroed scratch (fully written before read, every launch)
    unsigned* slotidx = (unsigned*)alloc(MM * 4);
    int* lab = (int*)alloc(MM * 4);
    unsigned long long* rowhash = (unsigned long long*)alloc(NN * 8);
    unsigned long long* colhash = (unsigned long long*)alloc(NN * 8);
    int* rvec = (int*)alloc(NN * 4);
    int* cvec = (int*)alloc(NN * 4);
    unsigned* rank0 = (unsigned*)alloc(512 * 4);

    (void)hipMemsetAsync(d_ws, 0, zero_end, stream);

    build_adj<<<(E + 255) / 256, 256, 0, stream>>>(ei, A, E);
    init_key_pass<<<MM / 256, 256, 0, stream>>>(x, A, mp0, c0, out);
    rank0_fused<<<1, 512, 0, stream>>>(mp0, c0, rank0, out);

    for (int layer = 0; layer < 2; ++layer) {
        int* hist = out + (size_t)(layer + 1) * MM;
        hash_both<<<2 * NN, NN, 0, stream>>>(x, A, rank0, lab, layer, rowhash, colhash);
        rep_hash<<<1, 512, 0, stream>>>(rowhash, colhash, rvec, cvec);
        relabel_insert<<<MM / 256, 256, 0, stream>>>(x, A, rank0, lab, layer, rvec, cvec,
                                                     tkL[layer], mpL[layer], cntL[layer],
                                                     slotidx);
        mark_bm<<<TBL / 256, 256, 0, stream>>>(tkL[layer], mpL[layer], bmL[layer], hist);
        finish_bm<<<TBL / 256, 256, 0, stream>>>(tkL[layer], mpL[layer], cntL[layer], bmL[layer],
                                                 slotidx, hist, lab);
    }
}